// Round 12
// baseline (460.846 us; speedup 1.0000x reference)
//
#include <hip/hip_runtime.h>
#include <hip/hip_bf16.h>
#include <stdint.h>

#define B_ 8
#define L_ 1024
#define H_ 768
#define E_ 16
#define W_ 504
#define DFF_ 512
#define N_ 5982
#define NE_ (N_*E_)    // 95712 candidates per batch
#define BNE_ (B_*NE_)  // 765696
#define MAXK48 0x0000FFFFFFFFFFFFull
#define PT_ 24         // per-thread candidate slots (24*256 = 6144 >= N_)

typedef unsigned long long u64;
typedef unsigned int u32;

__device__ __forceinline__ int rowstart_of(int s){
    int s0 = W_ - 11; // 493
    if (s <= s0) return 12*s;
    int t = s - s0;
    return 12*s0 + t*11 - (t*(t-1))/2;
}

// ---------------- prolog: span tables + tokc zero (block 8), parallel entpos (blocks 0..7) ----
__global__ void k_prolog(const int* __restrict__ ent_mask, int* __restrict__ ent_pos,
                         int* __restrict__ starts, int* __restrict__ ends,
                         int* __restrict__ tokc){
    int blk = blockIdx.x; int tid = threadIdx.x;
    if (blk == 8){
        for (int s = tid; s < W_; s += 256){
            int rs = rowstart_of(s);
            int cnt = min(12, W_ - s);
            for (int i = 0; i < cnt; i++){ starts[rs+i] = s; ends[rs+i] = s+i; }
        }
        for (int i = tid; i < B_*W_; i += 256) tokc[i] = 0;
        return;
    }
    __shared__ u32 wt[4]; __shared__ u32 cbase;
    int b = blk;
    int lane = tid & 63, wave = tid >> 6;
    if (tid == 0) cbase = 0;
    __syncthreads();
    for (int base = 0; base < L_; base += 256){
        int l = base + tid;
        bool f = (ent_mask[b*L_ + l] == 1);
        u64 bal = __ballot(f);
        if (lane == 0) wt[wave] = (u32)__popcll(bal);
        __syncthreads();
        u32 pre = cbase;
        for (int w = 0; w < 4; w++) if (w < wave) pre += wt[w];
        if (f){
            u32 rank = pre + (u32)__popcll(bal & ((1ull<<lane)-1ull));
            if (rank < E_) ent_pos[b*E_ + rank] = l;
        }
        __syncthreads();
        if (tid == 0){ u32 r = cbase; for (int w = 0; w < 4; w++) r += wt[w]; cbase = r; }
        __syncthreads();
    }
    u32 totEnt = cbase;
    if (totEnt >= E_) return;                 // block-uniform
    for (int base = 0; base < L_; base += 256){
        int l = base + tid;
        bool f = (ent_mask[b*L_ + l] != 1);
        u64 bal = __ballot(f);
        if (lane == 0) wt[wave] = (u32)__popcll(bal);
        __syncthreads();
        u32 pre = cbase;
        for (int w = 0; w < 4; w++) if (w < wave) pre += wt[w];
        if (f){
            u32 rank = pre + (u32)__popcll(bal & ((1ull<<lane)-1ull));
            if (rank < E_) ent_pos[b*E_ + rank] = l;
        }
        __syncthreads();
        if (tid == 0){ u32 r = cbase; for (int w = 0; w < 4; w++) r += wt[w]; cbase = r; }
        __syncthreads();
    }
}

// ---------------- token lists: parallel build ----------------
__global__ void k_toklist(const int* __restrict__ tm, const int* __restrict__ wi,
                          int* __restrict__ tok, int* __restrict__ tokc){
    int i = blockIdx.x*256 + threadIdx.x;
    if (i >= B_*L_) return;
    int w = wi[i];
    if (tm[i] == 1 && w >= 0 && w < W_){
        int b = i / L_;
        int bw = b*W_ + w;
        int pos = atomicAdd(&tokc[bw], 1);
        if (pos < 4) tok[bw*4 + pos] = i - b*L_;
    }
}

// ---------------- fused per-word sort + mean pooling (one block per (b,w)) ----------------
__global__ void k_poolsort(const float* __restrict__ hs, const int* __restrict__ tok,
                           const int* __restrict__ tokc, float* __restrict__ wemb){
    __shared__ int stok[4]; __shared__ int scnt;
    int bw = blockIdx.x;                       // B_*W_
    int b = bw / W_;
    int tid = threadIdx.x;
    if (tid == 0){
        int c = tokc[bw]; int cc = min(c, 4);
        int v[4];
        for (int k = 0; k < cc; k++) v[k] = tok[bw*4 + k];
        for (int a = 1; a < cc; a++){ int x = v[a]; int j = a-1; while (j >= 0 && v[j] > x){ v[j+1] = v[j]; j--; } v[j+1] = x; }
        for (int k = 0; k < cc; k++) stok[k] = v[k];
        scnt = c;
    }
    __syncthreads();
    int c = scnt; int cc = min(c, 4);
    float denom = (float)max(c, 1);
    for (int h = tid; h < H_; h += 256){
        double s = 0.0;
        for (int k = 0; k < cc; k++)
            s += (double)hs[((size_t)(b*L_ + stok[k]))*H_ + h];
        wemb[(size_t)bw*H_ + h] = (float)(s / (double)denom);
    }
}

// ---------------- entity MLP layer 1 (one output/thread; deep load pipeline) ----------------
__global__ void k_ent1(const float* __restrict__ hs, const int* __restrict__ ent_pos,
                       const float* __restrict__ w1, const float* __restrict__ b1,
                       float* __restrict__ hidg){
    __shared__ float x[H_];
    int blk = blockIdx.x;            // 256 blocks: be*2 + half
    int be = blk >> 1; int half = blk & 1;
    int b = be >> 4;
    int tid = threadIdx.x;
    int pos = ent_pos[be];
    const float* xp = hs + ((size_t)b*L_ + pos)*H_;
    for (int j = tid; j < H_; j += 256) x[j] = xp[j];
    __syncthreads();
    int d = half*256 + tid;
    float a0=0.f,a1=0.f,a2=0.f,a3=0.f;
    const float* wp = w1 + d;
    #pragma unroll 8
    for (int h = 0; h < H_; h += 4){
        a0 += x[h+0]*wp[(size_t)(h+0)*DFF_];
        a1 += x[h+1]*wp[(size_t)(h+1)*DFF_];
        a2 += x[h+2]*wp[(size_t)(h+2)*DFF_];
        a3 += x[h+3]*wp[(size_t)(h+3)*DFF_];
    }
    float acc = ((a0+a1)+(a2+a3)) + b1[d];
    hidg[(size_t)be*DFF_ + d] = acc > 0.f ? acc : 0.01f*acc;
}

// ---------------- entity MLP layer 2 (one output/thread; deep load pipeline) ----------------
__global__ void k_ent2(const float* __restrict__ hidg,
                       const float* __restrict__ w2, const float* __restrict__ b2,
                       float* __restrict__ ent_vec){
    __shared__ float hsd[DFF_];
    int blk = blockIdx.x;            // 384 blocks: be*3 + third
    int be = blk / 3; int third = blk % 3;
    int tid = threadIdx.x;
    const float* hp = hidg + (size_t)be*DFF_;
    for (int j = tid; j < DFF_; j += 256) hsd[j] = hp[j];
    __syncthreads();
    int j = third*256 + tid;
    float a0=0.f,a1=0.f,a2=0.f,a3=0.f;
    const float* wp = w2 + j;
    #pragma unroll 8
    for (int d = 0; d < DFF_; d += 4){
        a0 += hsd[d+0]*wp[(size_t)(d+0)*H_];
        a1 += hsd[d+1]*wp[(size_t)(d+1)*H_];
        a2 += hsd[d+2]*wp[(size_t)(d+2)*H_];
        a3 += hsd[d+3]*wp[(size_t)(d+3)*H_];
    }
    ent_vec[(size_t)be*H_ + j] = ((a0+a1)+(a2+a3)) + b2[j];
}

// ---------------- fused M + c: blocks 0..255 = M, block 256 = c (fp64, decode-critical) ------
__global__ void k_Mc(const float* __restrict__ span_w2, const float* __restrict__ span_b2,
                     const float* __restrict__ ent_vec, float* __restrict__ M,
                     float* __restrict__ cvec){
    int blk = blockIdx.x;
    if (blk == 256){
        int i = threadIdx.x;
        if (i < B_*E_){
            const float* ev = ent_vec + (size_t)i*H_;
            double acc = 0.0;
            for (int h = 0; h < H_; h++) acc += (double)span_b2[h]*(double)ev[h];
            cvec[i] = (float)acc;
        }
        return;
    }
    int b = blk/32; int dbase = (blk%32)*16;
    int tid = threadIdx.x; int d = dbase + (tid>>4); int e = tid&15;
    const float* ev = ent_vec + ((size_t)b*E_ + e)*H_;
    const float* wr = span_w2 + (size_t)d*H_;
    double p0=0.0, p1=0.0;
    for (int h = 0; h < H_; h += 2){
        p0 += (double)wr[h]*(double)ev[h];
        p1 += (double)wr[h+1]*(double)ev[h+1];
    }
    M[((size_t)b*DFF_ + d)*E_ + e] = (float)(p0+p1);
}

// ---------------- P/Q projection: BK=32 + register-prefetch double buffering ----------------
__global__ void k_pq(const float* __restrict__ wemb, const float* __restrict__ w1,
                     float* __restrict__ PQ, int b0){
    __shared__ float As[32][68];
    __shared__ float Bs[32][68];
    int bx = blockIdx.x & 15;      // col tile
    int by = blockIdx.x >> 4;      // row tile (0..31)
    int tid = threadIdx.x;
    int tm = tid >> 4, tn = tid & 15;
    const float* A0 = wemb + (size_t)b0*W_*H_;
    int colbase = bx*64;
    const float* Bbase = (colbase < DFF_) ? w1 : (w1 + (size_t)H_*DFF_);
    int bcol0 = (colbase < DFF_) ? colbase : (colbase - DFF_);
    float acc[4][4] = {{0.f}};
    int ar = tid >> 2, akq = tid & 3;
    int bkk = tid >> 4, bcq = tid & 15;
    const int ROWS = 4*W_;         // 2016
    int gr = by*64 + ar;
    bool aok = (gr < ROWS);
    const float* Ap = A0 + (size_t)gr*H_ + akq*4;
    const float* Bp = Bbase + (size_t)bkk*DFF_ + bcol0 + bcq*4;
    float4 av0, av1, bv0, bv1;
    av0 = aok ? *(const float4*)(Ap + 0)  : make_float4(0.f,0.f,0.f,0.f);
    av1 = aok ? *(const float4*)(Ap + 16) : make_float4(0.f,0.f,0.f,0.f);
    bv0 = *(const float4*)(Bp + 0);
    bv1 = *(const float4*)(Bp + (size_t)16*DFF_);
    for (int k0 = 0; k0 < H_; k0 += 32){
        As[akq*4+0][ar] = av0.x; As[akq*4+1][ar] = av0.y;
        As[akq*4+2][ar] = av0.z; As[akq*4+3][ar] = av0.w;
        As[16+akq*4+0][ar] = av1.x; As[16+akq*4+1][ar] = av1.y;
        As[16+akq*4+2][ar] = av1.z; As[16+akq*4+3][ar] = av1.w;
        Bs[bkk][bcq*4+0] = bv0.x; Bs[bkk][bcq*4+1] = bv0.y;
        Bs[bkk][bcq*4+2] = bv0.z; Bs[bkk][bcq*4+3] = bv0.w;
        Bs[16+bkk][bcq*4+0] = bv1.x; Bs[16+bkk][bcq*4+1] = bv1.y;
        Bs[16+bkk][bcq*4+2] = bv1.z; Bs[16+bkk][bcq*4+3] = bv1.w;
        __syncthreads();
        if (k0 + 32 < H_){        // prefetch next chunk; latency hides under compute
            int kn = k0 + 32;
            av0 = aok ? *(const float4*)(Ap + kn)      : make_float4(0.f,0.f,0.f,0.f);
            av1 = aok ? *(const float4*)(Ap + kn + 16) : make_float4(0.f,0.f,0.f,0.f);
            bv0 = *(const float4*)(Bp + (size_t)kn*DFF_);
            bv1 = *(const float4*)(Bp + (size_t)(kn+16)*DFF_);
        }
        #pragma unroll
        for (int kk = 0; kk < 32; kk++){
            float4 a = *(const float4*)&As[kk][tm*4];
            float4 bv = *(const float4*)&Bs[kk][tn*4];
            acc[0][0] += a.x*bv.x; acc[0][1] += a.x*bv.y; acc[0][2] += a.x*bv.z; acc[0][3] += a.x*bv.w;
            acc[1][0] += a.y*bv.x; acc[1][1] += a.y*bv.y; acc[1][2] += a.y*bv.z; acc[1][3] += a.y*bv.w;
            acc[2][0] += a.z*bv.x; acc[2][1] += a.z*bv.y; acc[2][2] += a.z*bv.z; acc[2][3] += a.z*bv.w;
            acc[3][0] += a.w*bv.x; acc[3][1] += a.w*bv.y; acc[3][2] += a.w*bv.z; acc[3][3] += a.w*bv.w;
        }
        __syncthreads();
    }
    #pragma unroll
    for (int r = 0; r < 4; r++){
        int grr = by*64 + tm*4 + r;
        if (grr < ROWS){
            float4 ov = make_float4(acc[r][0], acc[r][1], acc[r][2], acc[r][3]);
            *(float4*)(PQ + (size_t)grr*1024 + colbase + tn*4) = ov;
        }
    }
}

// ---------------- logits: one block per (bl, s); 4-way fp64 accum + wave-shuffle reduce ------
__global__ void k_logits(const float* __restrict__ PQ, const float* __restrict__ Mmat,
                         const float* __restrict__ cvec, const float* __restrict__ span_b1,
                         float* __restrict__ logits, float* __restrict__ outL, int b0){
    __shared__ float Ps[DFF_];
    __shared__ float hid[DFF_];
    __shared__ double redw[64];
    __shared__ float csh[E_];
    int blk = blockIdx.x;            // 4*W_ blocks
    int bl = blk / W_; int s = blk - bl*W_;
    int b = b0 + bl;
    int tid = threadIdx.x;
    int lane = tid & 63, wave = tid >> 6;
    int ee = tid & 15; int g = tid >> 4;   // 16 groups x 32 d
    float Mreg[32];
    {
        const float* Mp = Mmat + (size_t)b*DFF_*E_ + (size_t)(g*32)*E_ + ee;
        #pragma unroll
        for (int i = 0; i < 32; i++) Mreg[i] = Mp[(size_t)i*E_];
    }
    const float* P = PQ + ((size_t)(bl*W_ + s))*1024;
    for (int d = tid; d < DFF_; d += 256) Ps[d] = P[d] + span_b1[d];
    if (tid < E_) csh[tid] = cvec[b*E_ + tid];
    __syncthreads();
    int nsp = min(12, W_ - s);
    int nbase = rowstart_of(s);
    for (int i = 0; i < nsp; i++){
        int e = s + i;
        const float* Q = PQ + ((size_t)(bl*W_ + e))*1024 + DFF_;
        for (int d = tid; d < DFF_; d += 256){
            float h = Ps[d] + Q[d];
            hid[d] = h > 0.f ? h : 0.01f*h;
        }
        __syncthreads();
        {
            int d0 = g*32;
            double a0=0.0, a1=0.0, a2=0.0, a3=0.0;   // 4 chains break the serial FMA dep
            #pragma unroll
            for (int k = 0; k < 32; k += 4){
                a0 += (double)hid[d0+k+0]*(double)Mreg[k+0];
                a1 += (double)hid[d0+k+1]*(double)Mreg[k+1];
                a2 += (double)hid[d0+k+2]*(double)Mreg[k+2];
                a3 += (double)hid[d0+k+3]*(double)Mreg[k+3];
            }
            double acc = (a0+a1)+(a2+a3);
            double t = acc + __shfl_down(acc, 32, 64);
            t = t + __shfl_down(t, 16, 64);
            if (lane < 16) redw[wave*16 + lane] = t;
        }
        __syncthreads();
        if (tid < E_){
            double t = ((redw[tid] + redw[16+tid]) + (redw[32+tid] + redw[48+tid]))
                     + (double)csh[tid];
            float lg = (float)t;
            size_t oi = ((size_t)b*N_ + nbase + i)*E_ + tid;
            logits[oi] = lg;
            outL[oi] = lg;
        }
        __syncthreads();
    }
}

// ---------------- per-span best candidate + selected-region zeroing ----------------
__global__ void k_spanbest(const float* __restrict__ logits,
                           const int* __restrict__ starts, const int* __restrict__ ends,
                           u64* __restrict__ candS, float* __restrict__ outSel){
    int idx = blockIdx.x*256 + threadIdx.x;      // over B_*N_
    if (idx >= B_*N_) return;
    int b = idx / N_; int n = idx - b*N_;
    const float* lg = logits + (size_t)b*NE_ + (size_t)n*16;
    u64 best = ~0ull;
    for (int e = 0; e < 16; e++){
        float prob = 1.0f/(1.0f + expf(-lg[e]));
        if (prob > 0.5f){
            u32 key24 = (~__float_as_uint(prob)) & 0xFFFFFFu;
            u64 pk = ((u64)key24 << 24) | (u64)(u32)(n*16 + e);
            best = best < pk ? best : pk;
        }
    }
    int s = starts[n], e2 = ends[n];
    int len = e2 - s + 1;
    u64 packed = best;
    if (best != ~0ull)
        packed = best | ((u64)(u32)s << 48) | ((u64)(u32)(len-1) << 57);
    candS[idx] = packed;
    float* selp = outSel + (size_t)BNE_ + (size_t)b*NE_ + (size_t)n*16;
    float4 z = make_float4(0.f,0.f,0.f,0.f);
    *(float4*)(selp+0)  = z; *(float4*)(selp+4)  = z;
    *(float4*)(selp+8)  = z; *(float4*)(selp+12) = z;
}

// ---------------- tail: priority-MIS fixpoint == exact greedy decode (gather, no atomics) ----
// Per round: (1) mcov[w] = min key over SURVIVING candidates covering w, computed by GATHER
//            over the fixed 78-entry span structure (dead entries = MAXK48) — no atomics,
//            no same-address contention; (2) accept candidates that are the min on every
//            word of their span (exact-greedy-accepted; mutually disjoint); (3) kill alive
//            candidates overlapping accepted coverage. Accepted/killed entries are cleared
//            to ~0ull in the table by their OWNING thread only; cross-thread reads happen
//            only in the barrier-separated gather. Progress: the global-min survivor is
//            always accepted => terminates; decisions identical to sequential greedy.
__global__ __launch_bounds__(256) void k_tail(const u64* __restrict__ candS,
                                              float* __restrict__ outSel){
    __shared__ u64 cs[6144];     // 49,152 B candidate table (dead = ~0ull)
    __shared__ u64 mcov[512];    //  4,096 B per-word min key
    __shared__ u32 cov[512];     //  2,048 B accepted-coverage flags
    int b = blockIdx.x; int tid = threadIdx.x;
    const u64* cSg = candS + (size_t)b*N_;
    u32 alive = 0;
    #pragma unroll
    for (int k = 0; k < PT_; k++){
        int i = tid + (k << 8);
        u64 v = (i < N_) ? cSg[i] : ~0ull;
        cs[i] = v;
        if (v != ~0ull) alive |= (1u << k);
    }
    __syncthreads();
    while (true){
        // ---- phase 1: mcov gather (78 structurally-fixed reads per word) ----
        #pragma unroll
        for (int q = 0; q < 2; q++){
            int w = tid + q*256;          // 0..511
            u64 m = ~0ull;
            if (w < W_){
                int slo = (w > 11) ? (w - 11) : 0;
                for (int s = slo; s <= w; s++){
                    int rs = rowstart_of(s);
                    int lmax = min(12, W_ - s);
                    for (int l = w - s + 1; l <= lmax; l++){
                        u64 kk = cs[rs + l - 1] & MAXK48;   // dead -> MAXK48 (infinity)
                        if (kk < m) m = kk;
                    }
                }
            }
            mcov[w] = m;
            cov[w] = 0u;
        }
        __syncthreads();
        // ---- phase 2: accept clean candidates (min on every covered word) ----
        u32 accm = 0;
        u32 am = alive;
        while (am){
            int k = __builtin_ctz(am); am &= am - 1u;
            int i = tid + (k << 8);
            u64 v = cs[i];
            int s   = (int)((v >> 48) & 0x1FFull);
            int len = (int)((v >> 57) & 0xFull) + 1;
            u64 key = v & MAXK48;
            u64 rmin = ~0ull;
            for (int w = s; w < s + len; w++){ u64 t = mcov[w]; if (t < rmin) rmin = t; }
            if (rmin == key){
                accm |= (1u << k);
                for (int w = s; w < s + len; w++) cov[w] = 1u;   // disjoint -> race-free
                u32 c = (u32)(v & 0xFFFFFFull);
                outSel[(size_t)BNE_ + (size_t)b*NE_ + (size_t)c] = 1.0f;
                cs[i] = ~0ull;                                    // own slot only
            }
        }
        alive &= ~accm;
        __syncthreads();
        // ---- phase 3: kill alive candidates overlapping accepted coverage ----
        u32 killm = 0;
        am = alive;
        while (am){
            int k = __builtin_ctz(am); am &= am - 1u;
            int i = tid + (k << 8);
            u64 v = cs[i];
            int s   = (int)((v >> 48) & 0x1FFull);
            int len = (int)((v >> 57) & 0xFull) + 1;
            u32 f = 0;
            for (int w = s; w < s + len; w++) f |= cov[w];
            if (f){ killm |= (1u << k); cs[i] = ~0ull; }          // own slot only
        }
        alive &= ~killm;
        int na = __syncthreads_count(alive != 0u);
        if (na == 0) break;
    }
}

extern "C" void kernel_launch(void* const* d_in, const int* in_sizes, int n_in,
                              void* d_out, int out_size, void* d_ws, size_t ws_size,
                              hipStream_t stream){
    const float* hs        = (const float*)d_in[0];
    const float* ent_w1    = (const float*)d_in[1];
    const float* ent_b1    = (const float*)d_in[2];
    const float* ent_w2    = (const float*)d_in[3];
    const float* ent_b2    = (const float*)d_in[4];
    const float* span_w1   = (const float*)d_in[5];
    const float* span_b1   = (const float*)d_in[6];
    const float* span_w2   = (const float*)d_in[7];
    const float* span_b2   = (const float*)d_in[8];
    const int*  text_mask  = (const int*)d_in[9];
    const int*  ent_mask   = (const int*)d_in[10];
    const int*  word_index = (const int*)d_in[11];
    float* out = (float*)d_out;

    // ---- workspace (~24.8 MB peak; candS overlays dead wemb) ----
    char* wsbase = (char*)d_ws; size_t off = 0;
    auto alloc = [&](size_t bytes)->void*{ void* p = wsbase + off; off = (off + bytes + 255) & ~(size_t)255; return p; };
    char*  region1 = (char*)alloc((size_t)B_*W_*H_*4);    // 12,386,304 B
    float* wemb   = (float*)region1;                       // phase 1
    u64*   candS  = (u64*)region1;                         // phase 2: 382,848 B
    int*   tok    = (int*)  alloc((size_t)B_*W_*4*4);
    int*   tokc   = (int*)  alloc((size_t)B_*W_*4);
    float* PQ     = (float*)alloc((size_t)4*W_*1024*4);    // 8,257,536 B (4 batches/pass)
    float* logits = (float*)alloc((size_t)BNE_*4);         // 3,062,784 B
    int*   entpos = (int*)  alloc((size_t)B_*E_*4);
    float* hidg   = (float*)alloc((size_t)B_*E_*DFF_*4);   // 262,144 B
    float* entvec = (float*)alloc((size_t)B_*E_*H_*4);
    float* Mmat   = (float*)alloc((size_t)B_*DFF_*E_*4);
    float* cvec   = (float*)alloc((size_t)B_*E_*4);
    int*   starts = (int*)  alloc((size_t)N_*4);
    int*   ends   = (int*)  alloc((size_t)N_*4);

    k_prolog<<<9,256,0,stream>>>(ent_mask, entpos, starts, ends, tokc);
    k_toklist<<<(B_*L_+255)/256,256,0,stream>>>(text_mask, word_index, tok, tokc);
    k_poolsort<<<B_*W_,256,0,stream>>>(hs, tok, tokc, wemb);
    k_ent1<<<B_*E_*2,256,0,stream>>>(hs, entpos, ent_w1, ent_b1, hidg);
    k_ent2<<<B_*E_*3,256,0,stream>>>(hidg, ent_w2, ent_b2, entvec);
    k_Mc<<<257,256,0,stream>>>(span_w2, span_b2, entvec, Mmat, cvec);
    for (int b0 = 0; b0 < B_; b0 += 4){
        k_pq<<<512,256,0,stream>>>(wemb, span_w1, PQ, b0);
        k_logits<<<4*W_,256,0,stream>>>(PQ, Mmat, cvec, span_b1, logits, out, b0);
    }
    // wemb dead from here; region1 hosts candS
    k_spanbest<<<(B_*N_+255)/256,256,0,stream>>>(logits, starts, ends, candS, out);
    k_tail<<<B_,256,0,stream>>>(candS, out);
}